// Round 4
// baseline (498.897 us; speedup 1.0000x reference)
//
#include <hip/hip_runtime.h>

#define NN 50000
#define EE 500000
#define FD 128
#define HD 64
#define NET 3

// ---------------- CSR build ----------------

__global__ void k_count(const int* __restrict__ d0, const int* __restrict__ d1,
                        const int* __restrict__ d2, int* __restrict__ cnt) {
    int t = blockIdx.x * 256 + threadIdx.x;
    if (t >= NET * EE) return;
    int et = t / EE;
    int e  = t - et * EE;
    const int* d = (et == 0) ? d0 : ((et == 1) ? d1 : d2);
    atomicAdd(&cnt[et * NN + d[e]], 1);
}

// 3-phase scan: per-thread chunk sum -> one 1024 LDS scan -> local prefix write.
#define SCAN_CH 49   // ceil(50000/1024)
__global__ void k_scan(const int* __restrict__ cnt, int* __restrict__ rowptr,
                       int* __restrict__ cursor) {
    __shared__ int sh[1024];
    int et = blockIdx.x;
    const int* c = cnt + et * NN;
    int* rp = rowptr + et * (NN + 1);
    int* cu = cursor + et * NN;
    int t = (int)threadIdx.x;
    int beg = t * SCAN_CH;
    int end = beg + SCAN_CH; if (end > NN) end = NN;
    int sum = 0;
    for (int i = beg; i < end; ++i) sum += c[i];
    sh[t] = sum;
    __syncthreads();
    for (int off = 1; off < 1024; off <<= 1) {
        int add = (t >= off) ? sh[t - off] : 0;
        __syncthreads();
        sh[t] += add;
        __syncthreads();
    }
    int excl = sh[t] - sum;
    int total = sh[1023];
    int run = excl;
    for (int i = beg; i < end; ++i) {
        rp[i] = run; cu[i] = run; run += c[i];
    }
    if (t == 0) rp[NN] = total;
}

__global__ void k_scatter(const int* __restrict__ s0, const int* __restrict__ d0,
                          const int* __restrict__ s1, const int* __restrict__ d1,
                          const int* __restrict__ s2, const int* __restrict__ d2,
                          int* __restrict__ cursor, int* __restrict__ col) {
    int t = blockIdx.x * 256 + threadIdx.x;
    if (t >= NET * EE) return;
    int et = t / EE;
    int e  = t - et * EE;
    const int* s = (et == 0) ? s0 : ((et == 1) ? s1 : s2);
    const int* d = (et == 0) ? d0 : ((et == 1) ? d1 : d2);
    int dd = d[e];
    int pos = atomicAdd(&cursor[et * NN + dd], 1);
    col[et * EE + pos] = s[e];
}

// ---------------- Layer 0 (+ fused sim head) ----------------
// One 32-lane group per node; lane holds dims [4*l32,4*l32+3] (float4).
// Group-uniform control flow (shfl sources always active). 8 unconditional
// gathers in flight per group; tail edges masked via fmaf (same cost as add),
// dummy indices resolve to row 0 (L1-hot).

__global__ __launch_bounds__(256) void k_layer0(
    const float* __restrict__ feat, const float* __restrict__ Wm, const float* __restrict__ bm,
    const float* __restrict__ W0, const float* __restrict__ b0, const float* __restrict__ p0,
    const int* __restrict__ rowptr, const int* __restrict__ col,
    float* __restrict__ h1, float* __restrict__ simout) {
    __shared__ float hbuf[8][FD];      // 4 KiB
    int grp  = threadIdx.x >> 5;       // 8 nodes per block
    int l32  = threadIdx.x & 31;
    int d4   = l32 * 4;
    int node = (int)blockIdx.x * 8 + grp;   // 50000 % 8 == 0

    const float4 fr = *(const float4*)(feat + (size_t)node * FD + d4);

    float a0 = 0.f, a1 = 0.f, a2 = 0.f, a3 = 0.f;
    #pragma unroll
    for (int et = 0; et < NET; ++et) {
        const int* rp = rowptr + et * (NN + 1);
        int s = rp[node], t = rp[node + 1];
        const int* cc = col + et * EE;
        float x0 = 0.f, x1 = 0.f, x2 = 0.f, x3 = 0.f;
        for (int base = s; base < t; base += 32) {
            int idx = base + l32;
            int my = (idx < t) ? cc[idx] : 0;   // batched index load (group-wide)
            int m = t - base; if (m > 32) m = 32;
            for (int j = 0; j < m; j += 8) {
                int e0 = __shfl(my, j, 32);
                int e1 = __shfl(my, (j + 1) & 31, 32);
                int e2 = __shfl(my, (j + 2) & 31, 32);
                int e3 = __shfl(my, (j + 3) & 31, 32);
                int e4 = __shfl(my, (j + 4) & 31, 32);
                int e5 = __shfl(my, (j + 5) & 31, 32);
                int e6 = __shfl(my, (j + 6) & 31, 32);
                int e7 = __shfl(my, (j + 7) & 31, 32);
                float4 v0 = *(const float4*)(feat + (size_t)e0 * FD + d4);
                float4 v1 = *(const float4*)(feat + (size_t)e1 * FD + d4);
                float4 v2 = *(const float4*)(feat + (size_t)e2 * FD + d4);
                float4 v3 = *(const float4*)(feat + (size_t)e3 * FD + d4);
                float4 v4 = *(const float4*)(feat + (size_t)e4 * FD + d4);
                float4 v5 = *(const float4*)(feat + (size_t)e5 * FD + d4);
                float4 v6 = *(const float4*)(feat + (size_t)e6 * FD + d4);
                float4 v7 = *(const float4*)(feat + (size_t)e7 * FD + d4);
                float m1 = (j + 1 < m) ? 1.f : 0.f;
                float m2 = (j + 2 < m) ? 1.f : 0.f;
                float m3 = (j + 3 < m) ? 1.f : 0.f;
                float m4 = (j + 4 < m) ? 1.f : 0.f;
                float m5 = (j + 5 < m) ? 1.f : 0.f;
                float m6 = (j + 6 < m) ? 1.f : 0.f;
                float m7 = (j + 7 < m) ? 1.f : 0.f;
                x0 += v0.x; x1 += v0.y; x2 += v0.z; x3 += v0.w;
                x0 = fmaf(m1, v1.x, x0); x1 = fmaf(m1, v1.y, x1);
                x2 = fmaf(m1, v1.z, x2); x3 = fmaf(m1, v1.w, x3);
                x0 = fmaf(m2, v2.x, x0); x1 = fmaf(m2, v2.y, x1);
                x2 = fmaf(m2, v2.z, x2); x3 = fmaf(m2, v2.w, x3);
                x0 = fmaf(m3, v3.x, x0); x1 = fmaf(m3, v3.y, x1);
                x2 = fmaf(m3, v3.z, x2); x3 = fmaf(m3, v3.w, x3);
                x0 = fmaf(m4, v4.x, x0); x1 = fmaf(m4, v4.y, x1);
                x2 = fmaf(m4, v4.z, x2); x3 = fmaf(m4, v4.w, x3);
                x0 = fmaf(m5, v5.x, x0); x1 = fmaf(m5, v5.y, x1);
                x2 = fmaf(m5, v5.z, x2); x3 = fmaf(m5, v5.w, x3);
                x0 = fmaf(m6, v6.x, x0); x1 = fmaf(m6, v6.y, x1);
                x2 = fmaf(m6, v6.z, x2); x3 = fmaf(m6, v6.w, x3);
                x0 = fmaf(m7, v7.x, x0); x1 = fmaf(m7, v7.y, x1);
                x2 = fmaf(m7, v7.z, x2); x3 = fmaf(m7, v7.w, x3);
            }
        }
        int cdeg = t - s;
        float inv = 1.0f / (float)((cdeg > 0) ? cdeg : 1);
        float pe = p0[et];
        a0 += pe * tanhf(x0 * inv);
        a1 += pe * tanhf(x1 * inv);
        a2 += pe * tanhf(x2 * inv);
        a3 += pe * tanhf(x3 * inv);
    }
    float h0 = tanhf(a0 + fr.x);
    float hv1 = tanhf(a1 + fr.y);
    float h2 = tanhf(a2 + fr.z);
    float h3 = tanhf(a3 + fr.w);

    // sim = tanh(feat @ Wm + bm): per-lane 4-dim partial, butterfly in group.
    float sp0 = fr.x * Wm[(d4 + 0) * 2 + 0] + fr.y * Wm[(d4 + 1) * 2 + 0]
              + fr.z * Wm[(d4 + 2) * 2 + 0] + fr.w * Wm[(d4 + 3) * 2 + 0];
    float sp1 = fr.x * Wm[(d4 + 0) * 2 + 1] + fr.y * Wm[(d4 + 1) * 2 + 1]
              + fr.z * Wm[(d4 + 2) * 2 + 1] + fr.w * Wm[(d4 + 3) * 2 + 1];
    #pragma unroll
    for (int off = 16; off > 0; off >>= 1) {
        sp0 += __shfl_xor(sp0, off, 32);
        sp1 += __shfl_xor(sp1, off, 32);
    }
    if (l32 == 0) {
        simout[node * 2 + 0] = tanhf(sp0 + bm[0]);
        simout[node * 2 + 1] = tanhf(sp1 + bm[1]);
    }

    // h @ W0 + b0 : stage h row in LDS; lane computes output cols 2*l32, 2*l32+1.
    *(float4*)&hbuf[grp][d4] = make_float4(h0, hv1, h2, h3);
    __syncthreads();
    float2 o = *(const float2*)(b0 + 2 * l32);
    #pragma unroll 8
    for (int k = 0; k < FD; ++k) {
        float hk = hbuf[grp][k];                       // LDS broadcast
        float2 w = *(const float2*)(W0 + k * HD + 2 * l32);
        o.x = fmaf(hk, w.x, o.x);
        o.y = fmaf(hk, w.y, o.y);
    }
    *(float2*)(h1 + (size_t)node * HD + 2 * l32) = o;
}

// ---------------- Layer 1 ----------------
// One 16-lane group per node; lane holds dims [4*l16,4*l16+3] of the 64-dim
// row (float4). Same uniform-group + mask-FMA structure, 8 gathers in flight.

__global__ __launch_bounds__(256) void k_layer1(
    const float* __restrict__ h1, const float* __restrict__ W1, const float* __restrict__ b1,
    const float* __restrict__ p1, const int* __restrict__ rowptr, const int* __restrict__ col,
    float* __restrict__ out) {
    int grp = threadIdx.x >> 4;        // 16 nodes per block
    int l16 = threadIdx.x & 15;
    int d4  = l16 * 4;
    int node = (int)blockIdx.x * 16 + grp;   // 50000 % 16 == 0

    const float4 hr = *(const float4*)(h1 + (size_t)node * HD + d4);

    float a0 = 0.f, a1 = 0.f, a2 = 0.f, a3 = 0.f;
    #pragma unroll
    for (int et = 0; et < NET; ++et) {
        const int* rp = rowptr + et * (NN + 1);
        int s = rp[node], t = rp[node + 1];
        const int* cc = col + et * EE;
        float x0 = 0.f, x1 = 0.f, x2 = 0.f, x3 = 0.f;
        for (int base = s; base < t; base += 16) {
            int idx = base + l16;
            int my = (idx < t) ? cc[idx] : 0;
            int m = t - base; if (m > 16) m = 16;
            for (int j = 0; j < m; j += 8) {
                int e0 = __shfl(my, j, 16);
                int e1 = __shfl(my, (j + 1) & 15, 16);
                int e2 = __shfl(my, (j + 2) & 15, 16);
                int e3 = __shfl(my, (j + 3) & 15, 16);
                int e4 = __shfl(my, (j + 4) & 15, 16);
                int e5 = __shfl(my, (j + 5) & 15, 16);
                int e6 = __shfl(my, (j + 6) & 15, 16);
                int e7 = __shfl(my, (j + 7) & 15, 16);
                float4 v0 = *(const float4*)(h1 + (size_t)e0 * HD + d4);
                float4 v1 = *(const float4*)(h1 + (size_t)e1 * HD + d4);
                float4 v2 = *(const float4*)(h1 + (size_t)e2 * HD + d4);
                float4 v3 = *(const float4*)(h1 + (size_t)e3 * HD + d4);
                float4 v4 = *(const float4*)(h1 + (size_t)e4 * HD + d4);
                float4 v5 = *(const float4*)(h1 + (size_t)e5 * HD + d4);
                float4 v6 = *(const float4*)(h1 + (size_t)e6 * HD + d4);
                float4 v7 = *(const float4*)(h1 + (size_t)e7 * HD + d4);
                float m1 = (j + 1 < m) ? 1.f : 0.f;
                float m2 = (j + 2 < m) ? 1.f : 0.f;
                float m3 = (j + 3 < m) ? 1.f : 0.f;
                float m4 = (j + 4 < m) ? 1.f : 0.f;
                float m5 = (j + 5 < m) ? 1.f : 0.f;
                float m6 = (j + 6 < m) ? 1.f : 0.f;
                float m7 = (j + 7 < m) ? 1.f : 0.f;
                x0 += v0.x; x1 += v0.y; x2 += v0.z; x3 += v0.w;
                x0 = fmaf(m1, v1.x, x0); x1 = fmaf(m1, v1.y, x1);
                x2 = fmaf(m1, v1.z, x2); x3 = fmaf(m1, v1.w, x3);
                x0 = fmaf(m2, v2.x, x0); x1 = fmaf(m2, v2.y, x1);
                x2 = fmaf(m2, v2.z, x2); x3 = fmaf(m2, v2.w, x3);
                x0 = fmaf(m3, v3.x, x0); x1 = fmaf(m3, v3.y, x1);
                x2 = fmaf(m3, v3.z, x2); x3 = fmaf(m3, v3.w, x3);
                x0 = fmaf(m4, v4.x, x0); x1 = fmaf(m4, v4.y, x1);
                x2 = fmaf(m4, v4.z, x2); x3 = fmaf(m4, v4.w, x3);
                x0 = fmaf(m5, v5.x, x0); x1 = fmaf(m5, v5.y, x1);
                x2 = fmaf(m5, v5.z, x2); x3 = fmaf(m5, v5.w, x3);
                x0 = fmaf(m6, v6.x, x0); x1 = fmaf(m6, v6.y, x1);
                x2 = fmaf(m6, v6.z, x2); x3 = fmaf(m6, v6.w, x3);
                x0 = fmaf(m7, v7.x, x0); x1 = fmaf(m7, v7.y, x1);
                x2 = fmaf(m7, v7.z, x2); x3 = fmaf(m7, v7.w, x3);
            }
        }
        int cdeg = t - s;
        float inv = 1.0f / (float)((cdeg > 0) ? cdeg : 1);
        float pe = p1[et];
        a0 += pe * tanhf(x0 * inv);
        a1 += pe * tanhf(x1 * inv);
        a2 += pe * tanhf(x2 * inv);
        a3 += pe * tanhf(x3 * inv);
    }
    float g0 = tanhf(a0 + hr.x);
    float g1 = tanhf(a1 + hr.y);
    float g2 = tanhf(a2 + hr.z);
    float g3 = tanhf(a3 + hr.w);

    float q0 = g0 * W1[(d4 + 0) * 2 + 0] + g1 * W1[(d4 + 1) * 2 + 0]
             + g2 * W1[(d4 + 2) * 2 + 0] + g3 * W1[(d4 + 3) * 2 + 0];
    float q1 = g0 * W1[(d4 + 0) * 2 + 1] + g1 * W1[(d4 + 1) * 2 + 1]
             + g2 * W1[(d4 + 2) * 2 + 1] + g3 * W1[(d4 + 3) * 2 + 1];
    #pragma unroll
    for (int off = 8; off > 0; off >>= 1) {
        q0 += __shfl_xor(q0, off, 16);
        q1 += __shfl_xor(q1, off, 16);
    }
    if (l16 == 0) {
        out[node * 2 + 0] = q0 + b1[0];
        out[node * 2 + 1] = q1 + b1[1];
    }
}

// ---------------- launcher ----------------

extern "C" void kernel_launch(void* const* d_in, const int* in_sizes, int n_in,
                              void* d_out, int out_size, void* d_ws, size_t ws_size,
                              hipStream_t stream) {
    const float* feat = (const float*)d_in[0];
    const float* Wm   = (const float*)d_in[1];
    const float* bm   = (const float*)d_in[2];
    const float* W0   = (const float*)d_in[3];
    const float* b0   = (const float*)d_in[4];
    const float* W1   = (const float*)d_in[5];
    const float* b1   = (const float*)d_in[6];
    const float* p0   = (const float*)d_in[7];
    const float* p1   = (const float*)d_in[8];
    const int* src0 = (const int*)d_in[9];
    const int* dst0 = (const int*)d_in[10];
    const int* src1 = (const int*)d_in[11];
    const int* dst1 = (const int*)d_in[12];
    const int* src2 = (const int*)d_in[13];
    const int* dst2 = (const int*)d_in[14];

    char* ws = (char*)d_ws;
    // layout: cnt[3N] | rowptr[3(N+1)] | cursor[3N] | col[3E] | h1[N*HD]
    int*   cnt    = (int*)(ws + 0);           // 2,400,000 B
    int*   rowptr = (int*)(ws + 2400000);     //   600,016 B (padded)
    int*   cursor = (int*)(ws + 3000016);     // 2,400,000 B
    int*   col    = (int*)(ws + 5400016);     // 6,000,000 B
    float* h1     = (float*)(ws + 11400016);  // 12,800,000 B  (total ~24.2 MB)

    float* out = (float*)d_out;           // [N,2] first
    float* sim = out + (size_t)NN * 2;    // [N,2] second

    hipMemsetAsync(cnt, 0, sizeof(int) * NET * NN, stream);
    k_count<<<(NET * EE + 255) / 256, 256, 0, stream>>>(dst0, dst1, dst2, cnt);
    k_scan<<<NET, 1024, 0, stream>>>(cnt, rowptr, cursor);
    k_scatter<<<(NET * EE + 255) / 256, 256, 0, stream>>>(src0, dst0, src1, dst1, src2, dst2,
                                                          cursor, col);
    k_layer0<<<NN / 8, 256, 0, stream>>>(feat, Wm, bm, W0, b0, p0, rowptr, col, h1, sim);
    k_layer1<<<NN / 16, 256, 0, stream>>>(h1, W1, b1, p1, rowptr, col, out);
}

// Round 5
// 474.740 us; speedup vs baseline: 1.0509x; 1.0509x over previous
//
#include <hip/hip_runtime.h>

#define NN 50000
#define EE 500000
#define FD 128
#define HD 64
#define NET 3

__device__ __forceinline__ float bf2f(unsigned short u) {
    union { unsigned int i; float f; } c; c.i = ((unsigned int)u) << 16; return c.f;
}
__device__ __forceinline__ unsigned short f2bf(float f) {
    union { float f; unsigned int i; } c; c.f = f;
    unsigned int u = c.i;
    return (unsigned short)((u + 0x7fffu + ((u >> 16) & 1u)) >> 16);   // RNE
}

// ---------------- feat fp32 -> bf16 shadow ----------------
__global__ void k_cvt(const float* __restrict__ feat, unsigned short* __restrict__ featb) {
    int t = blockIdx.x * 256 + threadIdx.x;           // one float4 per thread
    if (t >= NN * FD / 4) return;
    float4 v = *(const float4*)(feat + t * 4);
    ushort4 o;
    o.x = f2bf(v.x); o.y = f2bf(v.y); o.z = f2bf(v.z); o.w = f2bf(v.w);
    *(ushort4*)(featb + t * 4) = o;
}

// ---------------- CSR build ----------------

__global__ void k_count(const int* __restrict__ d0, const int* __restrict__ d1,
                        const int* __restrict__ d2, int* __restrict__ cnt) {
    int t = blockIdx.x * 256 + threadIdx.x;
    if (t >= NET * EE) return;
    int et = t / EE;
    int e  = t - et * EE;
    const int* d = (et == 0) ? d0 : ((et == 1) ? d1 : d2);
    atomicAdd(&cnt[et * NN + d[e]], 1);
}

#define SCAN_CH 49   // ceil(50000/1024)
__global__ void k_scan(const int* __restrict__ cnt, int* __restrict__ rowptr,
                       int* __restrict__ cursor) {
    __shared__ int sh[1024];
    int et = blockIdx.x;
    const int* c = cnt + et * NN;
    int* rp = rowptr + et * (NN + 1);
    int* cu = cursor + et * NN;
    int t = (int)threadIdx.x;
    int beg = t * SCAN_CH;
    int end = beg + SCAN_CH; if (end > NN) end = NN;
    int sum = 0;
    for (int i = beg; i < end; ++i) sum += c[i];
    sh[t] = sum;
    __syncthreads();
    for (int off = 1; off < 1024; off <<= 1) {
        int add = (t >= off) ? sh[t - off] : 0;
        __syncthreads();
        sh[t] += add;
        __syncthreads();
    }
    int excl = sh[t] - sum;
    int total = sh[1023];
    int run = excl;
    for (int i = beg; i < end; ++i) {
        rp[i] = run; cu[i] = run; run += c[i];
    }
    if (t == 0) rp[NN] = total;
}

__global__ void k_scatter(const int* __restrict__ s0, const int* __restrict__ d0,
                          const int* __restrict__ s1, const int* __restrict__ d1,
                          const int* __restrict__ s2, const int* __restrict__ d2,
                          int* __restrict__ cursor, int* __restrict__ col) {
    int t = blockIdx.x * 256 + threadIdx.x;
    if (t >= NET * EE) return;
    int et = t / EE;
    int e  = t - et * EE;
    const int* s = (et == 0) ? s0 : ((et == 1) ? s1 : s2);
    const int* d = (et == 0) ? d0 : ((et == 1) ? d1 : d2);
    int dd = d[e];
    int pos = atomicAdd(&cursor[et * NN + dd], 1);
    col[et * EE + pos] = s[e];
}

// ---------------- Layer 0 (+ fused sim head) ----------------
// One 32-lane group per node; lane holds dims [4*l32,4*l32+3].
// Gathers read the bf16 shadow (8B/lane), accumulate fp32.
// Group-uniform control flow; 8 unconditional gathers in flight, mask-FMA tail.

__global__ __launch_bounds__(256) void k_layer0(
    const float* __restrict__ feat, const unsigned short* __restrict__ featb,
    const float* __restrict__ Wm, const float* __restrict__ bm,
    const float* __restrict__ W0, const float* __restrict__ b0, const float* __restrict__ p0,
    const int* __restrict__ rowptr, const int* __restrict__ col,
    unsigned short* __restrict__ h1b, float* __restrict__ simout) {
    __shared__ float hbuf[8][FD];      // 4 KiB
    int grp  = threadIdx.x >> 5;       // 8 nodes per block
    int l32  = threadIdx.x & 31;
    int d4   = l32 * 4;
    int node = (int)blockIdx.x * 8 + grp;   // 50000 % 8 == 0

    const float4 fr = *(const float4*)(feat + (size_t)node * FD + d4);

    float a0 = 0.f, a1 = 0.f, a2 = 0.f, a3 = 0.f;
    #pragma unroll
    for (int et = 0; et < NET; ++et) {
        const int* rp = rowptr + et * (NN + 1);
        int s = rp[node], t = rp[node + 1];
        const int* cc = col + et * EE;
        float x0 = 0.f, x1 = 0.f, x2 = 0.f, x3 = 0.f;
        for (int base = s; base < t; base += 32) {
            int idx = base + l32;
            int my = (idx < t) ? cc[idx] : 0;   // batched index load (group-wide)
            int m = t - base; if (m > 32) m = 32;
            for (int j = 0; j < m; j += 8) {
                int e0 = __shfl(my, j, 32);
                int e1 = __shfl(my, (j + 1) & 31, 32);
                int e2 = __shfl(my, (j + 2) & 31, 32);
                int e3 = __shfl(my, (j + 3) & 31, 32);
                int e4 = __shfl(my, (j + 4) & 31, 32);
                int e5 = __shfl(my, (j + 5) & 31, 32);
                int e6 = __shfl(my, (j + 6) & 31, 32);
                int e7 = __shfl(my, (j + 7) & 31, 32);
                ushort4 w0 = *(const ushort4*)(featb + (size_t)e0 * FD + d4);
                ushort4 w1 = *(const ushort4*)(featb + (size_t)e1 * FD + d4);
                ushort4 w2 = *(const ushort4*)(featb + (size_t)e2 * FD + d4);
                ushort4 w3 = *(const ushort4*)(featb + (size_t)e3 * FD + d4);
                ushort4 w4 = *(const ushort4*)(featb + (size_t)e4 * FD + d4);
                ushort4 w5 = *(const ushort4*)(featb + (size_t)e5 * FD + d4);
                ushort4 w6 = *(const ushort4*)(featb + (size_t)e6 * FD + d4);
                ushort4 w7 = *(const ushort4*)(featb + (size_t)e7 * FD + d4);
                float m1 = (j + 1 < m) ? 1.f : 0.f;
                float m2 = (j + 2 < m) ? 1.f : 0.f;
                float m3 = (j + 3 < m) ? 1.f : 0.f;
                float m4 = (j + 4 < m) ? 1.f : 0.f;
                float m5 = (j + 5 < m) ? 1.f : 0.f;
                float m6 = (j + 6 < m) ? 1.f : 0.f;
                float m7 = (j + 7 < m) ? 1.f : 0.f;
                x0 += bf2f(w0.x); x1 += bf2f(w0.y); x2 += bf2f(w0.z); x3 += bf2f(w0.w);
                x0 = fmaf(m1, bf2f(w1.x), x0); x1 = fmaf(m1, bf2f(w1.y), x1);
                x2 = fmaf(m1, bf2f(w1.z), x2); x3 = fmaf(m1, bf2f(w1.w), x3);
                x0 = fmaf(m2, bf2f(w2.x), x0); x1 = fmaf(m2, bf2f(w2.y), x1);
                x2 = fmaf(m2, bf2f(w2.z), x2); x3 = fmaf(m2, bf2f(w2.w), x3);
                x0 = fmaf(m3, bf2f(w3.x), x0); x1 = fmaf(m3, bf2f(w3.y), x1);
                x2 = fmaf(m3, bf2f(w3.z), x2); x3 = fmaf(m3, bf2f(w3.w), x3);
                x0 = fmaf(m4, bf2f(w4.x), x0); x1 = fmaf(m4, bf2f(w4.y), x1);
                x2 = fmaf(m4, bf2f(w4.z), x2); x3 = fmaf(m4, bf2f(w4.w), x3);
                x0 = fmaf(m5, bf2f(w5.x), x0); x1 = fmaf(m5, bf2f(w5.y), x1);
                x2 = fmaf(m5, bf2f(w5.z), x2); x3 = fmaf(m5, bf2f(w5.w), x3);
                x0 = fmaf(m6, bf2f(w6.x), x0); x1 = fmaf(m6, bf2f(w6.y), x1);
                x2 = fmaf(m6, bf2f(w6.z), x2); x3 = fmaf(m6, bf2f(w6.w), x3);
                x0 = fmaf(m7, bf2f(w7.x), x0); x1 = fmaf(m7, bf2f(w7.y), x1);
                x2 = fmaf(m7, bf2f(w7.z), x2); x3 = fmaf(m7, bf2f(w7.w), x3);
            }
        }
        int cdeg = t - s;
        float inv = 1.0f / (float)((cdeg > 0) ? cdeg : 1);
        float pe = p0[et];
        a0 += pe * tanhf(x0 * inv);
        a1 += pe * tanhf(x1 * inv);
        a2 += pe * tanhf(x2 * inv);
        a3 += pe * tanhf(x3 * inv);
    }
    float h0 = tanhf(a0 + fr.x);
    float hv1 = tanhf(a1 + fr.y);
    float h2 = tanhf(a2 + fr.z);
    float h3 = tanhf(a3 + fr.w);

    // sim = tanh(feat @ Wm + bm) in fp32
    float sp0 = fr.x * Wm[(d4 + 0) * 2 + 0] + fr.y * Wm[(d4 + 1) * 2 + 0]
              + fr.z * Wm[(d4 + 2) * 2 + 0] + fr.w * Wm[(d4 + 3) * 2 + 0];
    float sp1 = fr.x * Wm[(d4 + 0) * 2 + 1] + fr.y * Wm[(d4 + 1) * 2 + 1]
              + fr.z * Wm[(d4 + 2) * 2 + 1] + fr.w * Wm[(d4 + 3) * 2 + 1];
    #pragma unroll
    for (int off = 16; off > 0; off >>= 1) {
        sp0 += __shfl_xor(sp0, off, 32);
        sp1 += __shfl_xor(sp1, off, 32);
    }
    if (l32 == 0) {
        simout[node * 2 + 0] = tanhf(sp0 + bm[0]);
        simout[node * 2 + 1] = tanhf(sp1 + bm[1]);
    }

    // h @ W0 + b0 in fp32; store h1 row as bf16
    *(float4*)&hbuf[grp][d4] = make_float4(h0, hv1, h2, h3);
    __syncthreads();
    float2 o = *(const float2*)(b0 + 2 * l32);
    #pragma unroll 8
    for (int k = 0; k < FD; ++k) {
        float hk = hbuf[grp][k];                       // LDS broadcast
        float2 w = *(const float2*)(W0 + k * HD + 2 * l32);
        o.x = fmaf(hk, w.x, o.x);
        o.y = fmaf(hk, w.y, o.y);
    }
    ushort2 ob; ob.x = f2bf(o.x); ob.y = f2bf(o.y);
    *(ushort2*)(h1b + (size_t)node * HD + 2 * l32) = ob;
}

// ---------------- Layer 1 ----------------
// One 16-lane group per node; lane holds dims [4*l16,4*l16+3] of the 64-dim
// bf16 row (8B/lane). Same uniform-group + mask-FMA structure.

__global__ __launch_bounds__(256) void k_layer1(
    const unsigned short* __restrict__ h1b,
    const float* __restrict__ W1, const float* __restrict__ b1,
    const float* __restrict__ p1, const int* __restrict__ rowptr, const int* __restrict__ col,
    float* __restrict__ out) {
    int grp = threadIdx.x >> 4;        // 16 nodes per block
    int l16 = threadIdx.x & 15;
    int d4  = l16 * 4;
    int node = (int)blockIdx.x * 16 + grp;   // 50000 % 16 == 0

    ushort4 hru = *(const ushort4*)(h1b + (size_t)node * HD + d4);
    float hr0 = bf2f(hru.x), hr1 = bf2f(hru.y), hr2 = bf2f(hru.z), hr3 = bf2f(hru.w);

    float a0 = 0.f, a1 = 0.f, a2 = 0.f, a3 = 0.f;
    #pragma unroll
    for (int et = 0; et < NET; ++et) {
        const int* rp = rowptr + et * (NN + 1);
        int s = rp[node], t = rp[node + 1];
        const int* cc = col + et * EE;
        float x0 = 0.f, x1 = 0.f, x2 = 0.f, x3 = 0.f;
        for (int base = s; base < t; base += 16) {
            int idx = base + l16;
            int my = (idx < t) ? cc[idx] : 0;
            int m = t - base; if (m > 16) m = 16;
            for (int j = 0; j < m; j += 8) {
                int e0 = __shfl(my, j, 16);
                int e1 = __shfl(my, (j + 1) & 15, 16);
                int e2 = __shfl(my, (j + 2) & 15, 16);
                int e3 = __shfl(my, (j + 3) & 15, 16);
                int e4 = __shfl(my, (j + 4) & 15, 16);
                int e5 = __shfl(my, (j + 5) & 15, 16);
                int e6 = __shfl(my, (j + 6) & 15, 16);
                int e7 = __shfl(my, (j + 7) & 15, 16);
                ushort4 w0 = *(const ushort4*)(h1b + (size_t)e0 * HD + d4);
                ushort4 w1 = *(const ushort4*)(h1b + (size_t)e1 * HD + d4);
                ushort4 w2 = *(const ushort4*)(h1b + (size_t)e2 * HD + d4);
                ushort4 w3 = *(const ushort4*)(h1b + (size_t)e3 * HD + d4);
                ushort4 w4 = *(const ushort4*)(h1b + (size_t)e4 * HD + d4);
                ushort4 w5 = *(const ushort4*)(h1b + (size_t)e5 * HD + d4);
                ushort4 w6 = *(const ushort4*)(h1b + (size_t)e6 * HD + d4);
                ushort4 w7 = *(const ushort4*)(h1b + (size_t)e7 * HD + d4);
                float m1 = (j + 1 < m) ? 1.f : 0.f;
                float m2 = (j + 2 < m) ? 1.f : 0.f;
                float m3 = (j + 3 < m) ? 1.f : 0.f;
                float m4 = (j + 4 < m) ? 1.f : 0.f;
                float m5 = (j + 5 < m) ? 1.f : 0.f;
                float m6 = (j + 6 < m) ? 1.f : 0.f;
                float m7 = (j + 7 < m) ? 1.f : 0.f;
                x0 += bf2f(w0.x); x1 += bf2f(w0.y); x2 += bf2f(w0.z); x3 += bf2f(w0.w);
                x0 = fmaf(m1, bf2f(w1.x), x0); x1 = fmaf(m1, bf2f(w1.y), x1);
                x2 = fmaf(m1, bf2f(w1.z), x2); x3 = fmaf(m1, bf2f(w1.w), x3);
                x0 = fmaf(m2, bf2f(w2.x), x0); x1 = fmaf(m2, bf2f(w2.y), x1);
                x2 = fmaf(m2, bf2f(w2.z), x2); x3 = fmaf(m2, bf2f(w2.w), x3);
                x0 = fmaf(m3, bf2f(w3.x), x0); x1 = fmaf(m3, bf2f(w3.y), x1);
                x2 = fmaf(m3, bf2f(w3.z), x2); x3 = fmaf(m3, bf2f(w3.w), x3);
                x0 = fmaf(m4, bf2f(w4.x), x0); x1 = fmaf(m4, bf2f(w4.y), x1);
                x2 = fmaf(m4, bf2f(w4.z), x2); x3 = fmaf(m4, bf2f(w4.w), x3);
                x0 = fmaf(m5, bf2f(w5.x), x0); x1 = fmaf(m5, bf2f(w5.y), x1);
                x2 = fmaf(m5, bf2f(w5.z), x2); x3 = fmaf(m5, bf2f(w5.w), x3);
                x0 = fmaf(m6, bf2f(w6.x), x0); x1 = fmaf(m6, bf2f(w6.y), x1);
                x2 = fmaf(m6, bf2f(w6.z), x2); x3 = fmaf(m6, bf2f(w6.w), x3);
                x0 = fmaf(m7, bf2f(w7.x), x0); x1 = fmaf(m7, bf2f(w7.y), x1);
                x2 = fmaf(m7, bf2f(w7.z), x2); x3 = fmaf(m7, bf2f(w7.w), x3);
            }
        }
        int cdeg = t - s;
        float inv = 1.0f / (float)((cdeg > 0) ? cdeg : 1);
        float pe = p1[et];
        a0 += pe * tanhf(x0 * inv);
        a1 += pe * tanhf(x1 * inv);
        a2 += pe * tanhf(x2 * inv);
        a3 += pe * tanhf(x3 * inv);
    }
    float g0 = tanhf(a0 + hr0);
    float g1 = tanhf(a1 + hr1);
    float g2 = tanhf(a2 + hr2);
    float g3 = tanhf(a3 + hr3);

    float q0 = g0 * W1[(d4 + 0) * 2 + 0] + g1 * W1[(d4 + 1) * 2 + 0]
             + g2 * W1[(d4 + 2) * 2 + 0] + g3 * W1[(d4 + 3) * 2 + 0];
    float q1 = g0 * W1[(d4 + 0) * 2 + 1] + g1 * W1[(d4 + 1) * 2 + 1]
             + g2 * W1[(d4 + 2) * 2 + 1] + g3 * W1[(d4 + 3) * 2 + 1];
    #pragma unroll
    for (int off = 8; off > 0; off >>= 1) {
        q0 += __shfl_xor(q0, off, 16);
        q1 += __shfl_xor(q1, off, 16);
    }
    if (l16 == 0) {
        out[node * 2 + 0] = q0 + b1[0];
        out[node * 2 + 1] = q1 + b1[1];
    }
}

// ---------------- launcher ----------------

extern "C" void kernel_launch(void* const* d_in, const int* in_sizes, int n_in,
                              void* d_out, int out_size, void* d_ws, size_t ws_size,
                              hipStream_t stream) {
    const float* feat = (const float*)d_in[0];
    const float* Wm   = (const float*)d_in[1];
    const float* bm   = (const float*)d_in[2];
    const float* W0   = (const float*)d_in[3];
    const float* b0   = (const float*)d_in[4];
    const float* W1   = (const float*)d_in[5];
    const float* b1   = (const float*)d_in[6];
    const float* p0   = (const float*)d_in[7];
    const float* p1   = (const float*)d_in[8];
    const int* src0 = (const int*)d_in[9];
    const int* dst0 = (const int*)d_in[10];
    const int* src1 = (const int*)d_in[11];
    const int* dst1 = (const int*)d_in[12];
    const int* src2 = (const int*)d_in[13];
    const int* dst2 = (const int*)d_in[14];

    char* ws = (char*)d_ws;
    // layout: cnt[3N] | rowptr[3(N+1)] | cursor[3N] | col[3E] | featb[N*FD bf16] | h1b[N*HD bf16]
    int*            cnt    = (int*)(ws + 0);            // 2,400,000 B
    int*            rowptr = (int*)(ws + 2400000);      //   600,016 B (padded)
    int*            cursor = (int*)(ws + 3000016);      // 2,400,000 B
    int*            col    = (int*)(ws + 5400016);      // 6,000,000 B
    unsigned short* featb  = (unsigned short*)(ws + 11400016); // 12,800,000 B
    unsigned short* h1b    = (unsigned short*)(ws + 24200016); //  6,400,000 B  (~30.6 MB)

    float* out = (float*)d_out;           // [N,2] first
    float* sim = out + (size_t)NN * 2;    // [N,2] second

    hipMemsetAsync(cnt, 0, sizeof(int) * NET * NN, stream);
    k_cvt<<<(NN * FD / 4 + 255) / 256, 256, 0, stream>>>(feat, featb);
    k_count<<<(NET * EE + 255) / 256, 256, 0, stream>>>(dst0, dst1, dst2, cnt);
    k_scan<<<NET, 1024, 0, stream>>>(cnt, rowptr, cursor);
    k_scatter<<<(NET * EE + 255) / 256, 256, 0, stream>>>(src0, dst0, src1, dst1, src2, dst2,
                                                          cursor, col);
    k_layer0<<<NN / 8, 256, 0, stream>>>(feat, featb, Wm, bm, W0, b0, p0, rowptr, col, h1b, sim);
    k_layer1<<<NN / 16, 256, 0, stream>>>(h1b, W1, b1, p1, rowptr, col, out);
}

// Round 7
// 457.700 us; speedup vs baseline: 1.0900x; 1.0372x over previous
//
#include <hip/hip_runtime.h>

#define NN 50000
#define EE 500000
#define FD 128
#define HD 64
#define NET 3
#define CSTRIDE 656000   // padded col stride per etype (E + 3N = 650000 max)

__device__ __forceinline__ unsigned short f2bf(float f) {
    union { float f; unsigned int i; } c; c.f = f;
    unsigned int u = c.i;
    return (unsigned short)((u + 0x7fffu + ((u >> 16) & 1u)) >> 16);   // RNE
}
__device__ __forceinline__ float tanh_fast(float x) {
    // tanh(x) = 1 - 2/(e^{2x}+1); exp inf/0 limits give +/-1 correctly
    float e = __expf(2.0f * x);
    return 1.0f - __fdividef(2.0f, e + 1.0f);
}

// ---------------- prep: feat->bf16 shadow, zero pad rows, init col ----------------
// NOTE: grid must cover max(NN*FD/4 + 48, NET*CSTRIDE/4) threads (R6 bug: it
// only covered the col range, leaving 70% of featb unconverted).
#define PREP_T (NN * FD / 4 + 48)
__global__ void k_prep(const float* __restrict__ feat, unsigned short* __restrict__ featb,
                       unsigned short* __restrict__ h1b, int* __restrict__ col) {
    int t = blockIdx.x * 256 + threadIdx.x;
    if (t < NN * FD / 4) {                       // feat cvt, one float4 per thread
        float4 v = *(const float4*)(feat + (size_t)t * 4);
        ushort4 o;
        o.x = f2bf(v.x); o.y = f2bf(v.y); o.z = f2bf(v.z); o.w = f2bf(v.w);
        *(ushort4*)(featb + (size_t)t * 4) = o;
    } else if (t < NN * FD / 4 + 32) {           // zero row NN of featb
        int i = t - NN * FD / 4;
        *(ushort4*)(featb + (size_t)NN * FD + i * 4) = make_ushort4(0, 0, 0, 0);
    } else if (t < NN * FD / 4 + 48) {           // zero row NN of h1b
        int i = t - (NN * FD / 4 + 32);
        *(ushort4*)(h1b + (size_t)NN * HD + i * 4) = make_ushort4(0, 0, 0, 0);
    }
    if (t < NET * CSTRIDE / 4) {                 // init col with zero-row index
        *(int4*)(col + (size_t)t * 4) = make_int4(NN, NN, NN, NN);
    }
}

// ---------------- CSR build ----------------

__global__ void k_count(const int* __restrict__ d0, const int* __restrict__ d1,
                        const int* __restrict__ d2, int* __restrict__ cnt) {
    int t = blockIdx.x * 256 + threadIdx.x;
    if (t >= NET * EE) return;
    int et = t / EE;
    int e  = t - et * EE;
    const int* d = (et == 0) ? d0 : ((et == 1) ? d1 : d2);
    atomicAdd(&cnt[et * NN + d[e]], 1);
}

// 3-phase scan over counts PADDED to multiple of 4.
#define SCAN_CH 49   // ceil(50000/1024)
__global__ void k_scan(const int* __restrict__ cnt, int* __restrict__ rowptr,
                       int* __restrict__ cursor) {
    __shared__ int sh[1024];
    int et = blockIdx.x;
    const int* c = cnt + et * NN;
    int* rp = rowptr + et * (NN + 1);
    int* cu = cursor + et * NN;
    int t = (int)threadIdx.x;
    int beg = t * SCAN_CH;
    int end = beg + SCAN_CH; if (end > NN) end = NN;
    int sum = 0;
    for (int i = beg; i < end; ++i) sum += (c[i] + 3) & ~3;
    sh[t] = sum;
    __syncthreads();
    for (int off = 1; off < 1024; off <<= 1) {
        int add = (t >= off) ? sh[t - off] : 0;
        __syncthreads();
        sh[t] += add;
        __syncthreads();
    }
    int excl = sh[t] - sum;
    int total = sh[1023];
    int run = excl;
    for (int i = beg; i < end; ++i) {
        rp[i] = run; cu[i] = run; run += (c[i] + 3) & ~3;
    }
    if (t == 0) rp[NN] = total;
}

__global__ void k_scatter(const int* __restrict__ s0, const int* __restrict__ d0,
                          const int* __restrict__ s1, const int* __restrict__ d1,
                          const int* __restrict__ s2, const int* __restrict__ d2,
                          int* __restrict__ cursor, int* __restrict__ col) {
    int t = blockIdx.x * 256 + threadIdx.x;
    if (t >= NET * EE) return;
    int et = t / EE;
    int e  = t - et * EE;
    const int* s = (et == 0) ? s0 : ((et == 1) ? s1 : s2);
    const int* d = (et == 0) ? d0 : ((et == 1) ? d1 : d2);
    int dd = d[e];
    int pos = atomicAdd(&cursor[et * NN + dd], 1);
    col[(size_t)et * CSTRIDE + pos] = s[e];
}

// ---------------- Layer 0 (+ fused sim head) ----------------
// One 32-lane group per node; lane holds dims [4*l32,4*l32+3].
// Padded CSR: segments are multiples of 4, pad edges point at zero row NN ->
// no masks. 4 gathers in flight; fp32 accumulate; mean uses REAL cnt.

__global__ __launch_bounds__(256) void k_layer0(
    const float* __restrict__ feat, const unsigned short* __restrict__ featb,
    const float* __restrict__ Wm, const float* __restrict__ bm,
    const float* __restrict__ W0, const float* __restrict__ b0, const float* __restrict__ p0,
    const int* __restrict__ rowptr, const int* __restrict__ col, const int* __restrict__ cnt,
    unsigned short* __restrict__ h1b, float* __restrict__ simout) {
    __shared__ float hbuf[8][FD];      // 4 KiB
    int grp  = threadIdx.x >> 5;       // 8 nodes per block
    int l32  = threadIdx.x & 31;
    int d4   = l32 * 4;
    int node = (int)blockIdx.x * 8 + grp;   // 50000 % 8 == 0

    const float4 fr = *(const float4*)(feat + (size_t)node * FD + d4);

    float a0 = 0.f, a1 = 0.f, a2 = 0.f, a3 = 0.f;
    #pragma unroll
    for (int et = 0; et < NET; ++et) {
        const int* rp = rowptr + et * (NN + 1);
        int s = rp[node], t = rp[node + 1];
        const int* cc = col + (size_t)et * CSTRIDE;
        float x0 = 0.f, x1 = 0.f, x2 = 0.f, x3 = 0.f;
        for (int base = s; base < t; base += 32) {
            int idx = base + l32;
            int my = (idx < t) ? cc[idx] : NN;  // batched index load (group-wide)
            int m = t - base; if (m > 32) m = 32;   // m is a multiple of 4
            for (int j = 0; j < m; j += 4) {
                int e0 = __shfl(my, j, 32);
                int e1 = __shfl(my, j + 1, 32);
                int e2 = __shfl(my, j + 2, 32);
                int e3 = __shfl(my, j + 3, 32);
                uint2 u0 = *(const uint2*)(featb + (size_t)e0 * FD + d4);
                uint2 u1 = *(const uint2*)(featb + (size_t)e1 * FD + d4);
                uint2 u2 = *(const uint2*)(featb + (size_t)e2 * FD + d4);
                uint2 u3 = *(const uint2*)(featb + (size_t)e3 * FD + d4);
                x0 += __uint_as_float(u0.x << 16);
                x1 += __uint_as_float(u0.x & 0xffff0000u);
                x2 += __uint_as_float(u0.y << 16);
                x3 += __uint_as_float(u0.y & 0xffff0000u);
                x0 += __uint_as_float(u1.x << 16);
                x1 += __uint_as_float(u1.x & 0xffff0000u);
                x2 += __uint_as_float(u1.y << 16);
                x3 += __uint_as_float(u1.y & 0xffff0000u);
                x0 += __uint_as_float(u2.x << 16);
                x1 += __uint_as_float(u2.x & 0xffff0000u);
                x2 += __uint_as_float(u2.y << 16);
                x3 += __uint_as_float(u2.y & 0xffff0000u);
                x0 += __uint_as_float(u3.x << 16);
                x1 += __uint_as_float(u3.x & 0xffff0000u);
                x2 += __uint_as_float(u3.y << 16);
                x3 += __uint_as_float(u3.y & 0xffff0000u);
            }
        }
        int cdeg = cnt[et * NN + node];          // REAL degree (pads add zeros)
        float inv = 1.0f / (float)((cdeg > 0) ? cdeg : 1);
        float pe = p0[et];
        a0 += pe * tanh_fast(x0 * inv);
        a1 += pe * tanh_fast(x1 * inv);
        a2 += pe * tanh_fast(x2 * inv);
        a3 += pe * tanh_fast(x3 * inv);
    }
    float h0 = tanh_fast(a0 + fr.x);
    float hv1 = tanh_fast(a1 + fr.y);
    float h2 = tanh_fast(a2 + fr.z);
    float h3 = tanh_fast(a3 + fr.w);

    // sim = tanh(feat @ Wm + bm) in fp32
    float sp0 = fr.x * Wm[(d4 + 0) * 2 + 0] + fr.y * Wm[(d4 + 1) * 2 + 0]
              + fr.z * Wm[(d4 + 2) * 2 + 0] + fr.w * Wm[(d4 + 3) * 2 + 0];
    float sp1 = fr.x * Wm[(d4 + 0) * 2 + 1] + fr.y * Wm[(d4 + 1) * 2 + 1]
              + fr.z * Wm[(d4 + 2) * 2 + 1] + fr.w * Wm[(d4 + 3) * 2 + 1];
    #pragma unroll
    for (int off = 16; off > 0; off >>= 1) {
        sp0 += __shfl_xor(sp0, off, 32);
        sp1 += __shfl_xor(sp1, off, 32);
    }
    if (l32 == 0) {
        simout[node * 2 + 0] = tanh_fast(sp0 + bm[0]);
        simout[node * 2 + 1] = tanh_fast(sp1 + bm[1]);
    }

    // h @ W0 + b0 in fp32 (hbuf via ds_read_b128); store h1 row as bf16
    *(float4*)&hbuf[grp][d4] = make_float4(h0, hv1, h2, h3);
    __syncthreads();
    float2 o = *(const float2*)(b0 + 2 * l32);
    #pragma unroll 8
    for (int k4 = 0; k4 < FD; k4 += 4) {
        float4 h4 = *(const float4*)&hbuf[grp][k4];
        float2 wa = *(const float2*)(W0 + (k4 + 0) * HD + 2 * l32);
        float2 wb = *(const float2*)(W0 + (k4 + 1) * HD + 2 * l32);
        float2 wc = *(const float2*)(W0 + (k4 + 2) * HD + 2 * l32);
        float2 wd = *(const float2*)(W0 + (k4 + 3) * HD + 2 * l32);
        o.x = fmaf(h4.x, wa.x, o.x); o.y = fmaf(h4.x, wa.y, o.y);
        o.x = fmaf(h4.y, wb.x, o.x); o.y = fmaf(h4.y, wb.y, o.y);
        o.x = fmaf(h4.z, wc.x, o.x); o.y = fmaf(h4.z, wc.y, o.y);
        o.x = fmaf(h4.w, wd.x, o.x); o.y = fmaf(h4.w, wd.y, o.y);
    }
    ushort2 ob; ob.x = f2bf(o.x); ob.y = f2bf(o.y);
    *(ushort2*)(h1b + (size_t)node * HD + 2 * l32) = ob;
}

// ---------------- Layer 1 ----------------
// One 16-lane group per node; lane holds dims [4*l16,4*l16+3] of the 64-dim
// bf16 row. Padded CSR, no masks, 4 gathers in flight.

__global__ __launch_bounds__(256) void k_layer1(
    const unsigned short* __restrict__ h1b,
    const float* __restrict__ W1, const float* __restrict__ b1,
    const float* __restrict__ p1, const int* __restrict__ rowptr,
    const int* __restrict__ col, const int* __restrict__ cnt,
    float* __restrict__ out) {
    int grp = threadIdx.x >> 4;        // 16 nodes per block
    int l16 = threadIdx.x & 15;
    int d4  = l16 * 4;
    int node = (int)blockIdx.x * 16 + grp;   // 50000 % 16 == 0

    uint2 hru = *(const uint2*)(h1b + (size_t)node * HD + d4);
    float hr0 = __uint_as_float(hru.x << 16);
    float hr1 = __uint_as_float(hru.x & 0xffff0000u);
    float hr2 = __uint_as_float(hru.y << 16);
    float hr3 = __uint_as_float(hru.y & 0xffff0000u);

    float a0 = 0.f, a1 = 0.f, a2 = 0.f, a3 = 0.f;
    #pragma unroll
    for (int et = 0; et < NET; ++et) {
        const int* rp = rowptr + et * (NN + 1);
        int s = rp[node], t = rp[node + 1];
        const int* cc = col + (size_t)et * CSTRIDE;
        float x0 = 0.f, x1 = 0.f, x2 = 0.f, x3 = 0.f;
        for (int base = s; base < t; base += 16) {
            int idx = base + l16;
            int my = (idx < t) ? cc[idx] : NN;
            int m = t - base; if (m > 16) m = 16;   // multiple of 4
            for (int j = 0; j < m; j += 4) {
                int e0 = __shfl(my, j, 16);
                int e1 = __shfl(my, j + 1, 16);
                int e2 = __shfl(my, j + 2, 16);
                int e3 = __shfl(my, j + 3, 16);
                uint2 u0 = *(const uint2*)(h1b + (size_t)e0 * HD + d4);
                uint2 u1 = *(const uint2*)(h1b + (size_t)e1 * HD + d4);
                uint2 u2 = *(const uint2*)(h1b + (size_t)e2 * HD + d4);
                uint2 u3 = *(const uint2*)(h1b + (size_t)e3 * HD + d4);
                x0 += __uint_as_float(u0.x << 16);
                x1 += __uint_as_float(u0.x & 0xffff0000u);
                x2 += __uint_as_float(u0.y << 16);
                x3 += __uint_as_float(u0.y & 0xffff0000u);
                x0 += __uint_as_float(u1.x << 16);
                x1 += __uint_as_float(u1.x & 0xffff0000u);
                x2 += __uint_as_float(u1.y << 16);
                x3 += __uint_as_float(u1.y & 0xffff0000u);
                x0 += __uint_as_float(u2.x << 16);
                x1 += __uint_as_float(u2.x & 0xffff0000u);
                x2 += __uint_as_float(u2.y << 16);
                x3 += __uint_as_float(u2.y & 0xffff0000u);
                x0 += __uint_as_float(u3.x << 16);
                x1 += __uint_as_float(u3.x & 0xffff0000u);
                x2 += __uint_as_float(u3.y << 16);
                x3 += __uint_as_float(u3.y & 0xffff0000u);
            }
        }
        int cdeg = cnt[et * NN + node];
        float inv = 1.0f / (float)((cdeg > 0) ? cdeg : 1);
        float pe = p1[et];
        a0 += pe * tanh_fast(x0 * inv);
        a1 += pe * tanh_fast(x1 * inv);
        a2 += pe * tanh_fast(x2 * inv);
        a3 += pe * tanh_fast(x3 * inv);
    }
    float g0 = tanh_fast(a0 + hr0);
    float g1 = tanh_fast(a1 + hr1);
    float g2 = tanh_fast(a2 + hr2);
    float g3 = tanh_fast(a3 + hr3);

    float q0 = g0 * W1[(d4 + 0) * 2 + 0] + g1 * W1[(d4 + 1) * 2 + 0]
             + g2 * W1[(d4 + 2) * 2 + 0] + g3 * W1[(d4 + 3) * 2 + 0];
    float q1 = g0 * W1[(d4 + 0) * 2 + 1] + g1 * W1[(d4 + 1) * 2 + 1]
             + g2 * W1[(d4 + 2) * 2 + 1] + g3 * W1[(d4 + 3) * 2 + 1];
    #pragma unroll
    for (int off = 8; off > 0; off >>= 1) {
        q0 += __shfl_xor(q0, off, 16);
        q1 += __shfl_xor(q1, off, 16);
    }
    if (l16 == 0) {
        out[node * 2 + 0] = q0 + b1[0];
        out[node * 2 + 1] = q1 + b1[1];
    }
}

// ---------------- launcher ----------------

extern "C" void kernel_launch(void* const* d_in, const int* in_sizes, int n_in,
                              void* d_out, int out_size, void* d_ws, size_t ws_size,
                              hipStream_t stream) {
    const float* feat = (const float*)d_in[0];
    const float* Wm   = (const float*)d_in[1];
    const float* bm   = (const float*)d_in[2];
    const float* W0   = (const float*)d_in[3];
    const float* b0   = (const float*)d_in[4];
    const float* W1   = (const float*)d_in[5];
    const float* b1   = (const float*)d_in[6];
    const float* p0   = (const float*)d_in[7];
    const float* p1   = (const float*)d_in[8];
    const int* src0 = (const int*)d_in[9];
    const int* dst0 = (const int*)d_in[10];
    const int* src1 = (const int*)d_in[11];
    const int* dst1 = (const int*)d_in[12];
    const int* src2 = (const int*)d_in[13];
    const int* dst2 = (const int*)d_in[14];

    char* ws = (char*)d_ws;
    // layout (16B-aligned offsets):
    int*            cnt    = (int*)(ws + 0);                   //   600,000 B
    int*            rowptr = (int*)(ws + 600000);              //   600,016 B
    int*            cursor = (int*)(ws + 1200016);             //   600,000 B
    int*            col    = (int*)(ws + 1800016);             // 7,872,000 B (3 x 656000 int)
    unsigned short* featb  = (unsigned short*)(ws + 9672016);  // 12,800,256 B ((N+1) rows)
    unsigned short* h1b    = (unsigned short*)(ws + 22472272); //  6,400,128 B ((N+1) rows)
    // total ~28.9 MB

    float* out = (float*)d_out;           // [N,2] first
    float* sim = out + (size_t)NN * 2;    // [N,2] second

    hipMemsetAsync(cnt, 0, sizeof(int) * NET * NN, stream);
    k_prep<<<(PREP_T + 255) / 256, 256, 0, stream>>>(feat, featb, h1b, col);
    k_count<<<(NET * EE + 255) / 256, 256, 0, stream>>>(dst0, dst1, dst2, cnt);
    k_scan<<<NET, 1024, 0, stream>>>(cnt, rowptr, cursor);
    k_scatter<<<(NET * EE + 255) / 256, 256, 0, stream>>>(src0, dst0, src1, dst1, src2, dst2,
                                                          cursor, col);
    k_layer0<<<NN / 8, 256, 0, stream>>>(feat, featb, Wm, bm, W0, b0, p0,
                                         rowptr, col, cnt, h1b, sim);
    k_layer1<<<NN / 16, 256, 0, stream>>>(h1b, W1, b1, p1, rowptr, col, cnt, out);
}